// Round 2
// baseline (157.642 us; speedup 1.0000x reference)
//
#include <hip/hip_runtime.h>
#include <hip/hip_cooperative_groups.h>
#include <math.h>

namespace cg = cooperative_groups;

// Fused quantization: one cooperative kernel.
// phase 1: grid-stride float4 min/max -> per-block partials
// grid.sync()
// phase 2: every block reduces the 1024 partials (L2-resident, ~us)
// phase 3: grid-stride quantize; x re-read hits L3 (134 MB < 256 MiB)

#define BLOCK 256
#define GRID 1024   // 4 blocks/CU on 256 CUs -- safe co-residency for cooperative launch

__global__ __launch_bounds__(BLOCK, 4) void fused_quant_kernel(
    const float* __restrict__ x, float* __restrict__ out, long long n,
    float* __restrict__ partial) {
    cg::grid_group grid = cg::this_grid();

    const long long tid = (long long)blockIdx.x * blockDim.x + threadIdx.x;
    const long long stride = (long long)gridDim.x * blockDim.x;
    const long long n4 = n >> 2;
    const float4* __restrict__ x4 = (const float4*)x;

    // ---- phase 1: local min/max ----
    float vmin = INFINITY, vmax = -INFINITY;
    for (long long i = tid; i < n4; i += stride) {
        float4 v = x4[i];
        vmin = fminf(vmin, fminf(fminf(v.x, v.y), fminf(v.z, v.w)));
        vmax = fmaxf(vmax, fmaxf(fmaxf(v.x, v.y), fmaxf(v.z, v.w)));
    }
    for (long long i = (n4 << 2) + tid; i < n; i += stride) {
        float v = x[i];
        vmin = fminf(vmin, v);
        vmax = fmaxf(vmax, v);
    }
    #pragma unroll
    for (int off = 32; off > 0; off >>= 1) {
        vmin = fminf(vmin, __shfl_down(vmin, off, 64));
        vmax = fmaxf(vmax, __shfl_down(vmax, off, 64));
    }
    __shared__ float smin[BLOCK / 64], smax[BLOCK / 64];
    __shared__ float s_xmin, s_xmax;
    const int lane = threadIdx.x & 63;
    const int wave = threadIdx.x >> 6;
    if (lane == 0) { smin[wave] = vmin; smax[wave] = vmax; }
    __syncthreads();
    if (threadIdx.x == 0) {
        float bmin = smin[0], bmax = smax[0];
        #pragma unroll
        for (int w = 1; w < BLOCK / 64; ++w) {
            bmin = fminf(bmin, smin[w]);
            bmax = fmaxf(bmax, smax[w]);
        }
        partial[blockIdx.x] = bmin;
        partial[GRID + blockIdx.x] = bmax;
    }

    grid.sync();

    // ---- phase 2: every block reduces all partials (16 KB, L2-hot) ----
    float pmin = INFINITY, pmax = -INFINITY;
    for (int i = threadIdx.x; i < GRID; i += BLOCK) {
        pmin = fminf(pmin, partial[i]);
        pmax = fmaxf(pmax, partial[GRID + i]);
    }
    #pragma unroll
    for (int off = 32; off > 0; off >>= 1) {
        pmin = fminf(pmin, __shfl_down(pmin, off, 64));
        pmax = fmaxf(pmax, __shfl_down(pmax, off, 64));
    }
    if (lane == 0) { smin[wave] = pmin; smax[wave] = pmax; }
    __syncthreads();
    if (threadIdx.x == 0) {
        float bmin = smin[0], bmax = smax[0];
        #pragma unroll
        for (int w = 1; w < BLOCK / 64; ++w) {
            bmin = fminf(bmin, smin[w]);
            bmax = fmaxf(bmax, smax[w]);
        }
        s_xmin = bmin;
        s_xmax = bmax;
    }
    __syncthreads();

    // ---- phase 3: quantize (x re-read is L3-resident) ----
    const float xmin = s_xmin;
    const float xmax = s_xmax;
    const float step = (xmax - xmin) * (1.0f / 256.0f);
    const float inv_step = 1.0f / step;
    float4* __restrict__ o4 = (float4*)out;

    for (long long i = tid; i < n4; i += stride) {
        float4 v = x4[i];
        float4 r;
        float ix = fminf(fmaxf(floorf((v.x - xmin) * inv_step), 0.0f), 255.0f);
        float iy = fminf(fmaxf(floorf((v.y - xmin) * inv_step), 0.0f), 255.0f);
        float iz = fminf(fmaxf(floorf((v.z - xmin) * inv_step), 0.0f), 255.0f);
        float iw = fminf(fmaxf(floorf((v.w - xmin) * inv_step), 0.0f), 255.0f);
        r.x = xmin + (ix + 0.5f) * step;
        r.y = xmin + (iy + 0.5f) * step;
        r.z = xmin + (iz + 0.5f) * step;
        r.w = xmin + (iw + 0.5f) * step;
        o4[i] = r;
    }
    for (long long i = (n4 << 2) + tid; i < n; i += stride) {
        float v = x[i];
        float idx = fminf(fmaxf(floorf((v - xmin) * inv_step), 0.0f), 255.0f);
        out[i] = xmin + (idx + 0.5f) * step;
    }
}

extern "C" void kernel_launch(void* const* d_in, const int* in_sizes, int n_in,
                              void* d_out, int out_size, void* d_ws, size_t ws_size,
                              hipStream_t stream) {
    const float* x = (const float*)d_in[0];
    float* out = (float*)d_out;
    long long n = (long long)in_sizes[0];
    float* partial = (float*)d_ws;  // [0..GRID) mins, [GRID..2*GRID) maxs

    void* args[] = {(void*)&x, (void*)&out, (void*)&n, (void*)&partial};
    hipLaunchCooperativeKernel((const void*)fused_quant_kernel,
                               dim3(GRID), dim3(BLOCK), args, 0, stream);
}